// Round 4
// baseline (148.783 us; speedup 1.0000x reference)
//
#include <hip/hip_runtime.h>

#define BATCH 4
#define NDIM 2048
#define MDIM 2048
#define CDIM 128
#define NROWS (BATCH * NDIM)   // 8192 rows per tensor

typedef short bf16x8 __attribute__((ext_vector_type(8)));   // 8 bf16 (4 VGPRs)
typedef float f32x4  __attribute__((ext_vector_type(4)));   // MFMA accumulator
typedef float f32x2  __attribute__((ext_vector_type(2)));   // NT store payload

// fp32 -> bf16 bits, round-to-nearest-even (inputs are finite normals).
__device__ __forceinline__ unsigned short f2bf(float f) {
    union { float f; unsigned int u; } v; v.f = f;
    unsigned int u = v.u;
    return (unsigned short)((u + 0x7FFFu + ((u >> 16) & 1u)) >> 16);
}

// 16B global->LDS DMA (no VGPR round-trip). LDS dest must be
// wave-uniform base + lane*16 -- our tid*16 layout satisfies this.
__device__ __forceinline__ void gload_lds16(const void* g, void* l) {
    __builtin_amdgcn_global_load_lds(
        (const __attribute__((address_space(1))) void*)g,
        (__attribute__((address_space(3))) void*)l, 16, 0, 0);
}

// Kernel 1 (prep): per-row fp32 norms AND one-time fp32->bf16 conversion,
// rows written PRE-SWIZZLED in 16B chunks (chunk ^ (row&15)) so sim can
// global_load_lds them linearly and read fragments with the XOR pattern.
// 32 lanes per row (one float4 each).
// ws layout: [0,2MB) src bf16 | [2MB,4MB) tgt bf16 | [4MB,+64KB) fp32 norms.
__global__ __launch_bounds__(256) void prep_kernel(
    const float* __restrict__ src, const float* __restrict__ tgt,
    unsigned short* __restrict__ bf, float* __restrict__ nrm)
{
    int gid = blockIdx.x * 256 + threadIdx.x;
    int row = gid >> 5;                 // 0..16383 (src then tgt)
    int l32 = gid & 31;
    const float* base = (row < NROWS)
        ? (src + (size_t)row * CDIM)
        : (tgt + (size_t)(row - NROWS) * CDIM);
    float4 v = ((const float4*)base)[l32];
    float s = v.x * v.x + v.y * v.y + v.z * v.z + v.w * v.w;
    #pragma unroll
    for (int off = 16; off >= 1; off >>= 1) s += __shfl_xor(s, off, 64);
    if (l32 == 0) nrm[row] = s;

    // swizzled bf16 store: chunk = 8 elems (16B); this lane owns half of one.
    int chunk = l32 >> 1;
    int half  = l32 & 1;
    unsigned short* dst = bf + (size_t)row * CDIM
                        + (((chunk ^ (row & 15)) << 3) + (half << 2));
    ushort4 u;
    u.x = f2bf(v.x); u.y = f2bf(v.y); u.z = f2bf(v.z); u.w = f2bf(v.w);
    *(ushort4*)dst = u;
}

// Kernel 2: 64x64 output tile (LDS 32 KiB -> 5 blocks/CU for store-pipe
// stagger). Staging = pure global_load_lds DMA of pre-swizzled bf16 rows.
// 4 waves of 32x32 quadrants. Nontemporal output stores (write-once data;
// keeps the 4 MB bf16 working set L2-resident). Bijective XCD chunk swizzle:
// 4096 blocks = 8 XCDs x 512, each chunk's reads ~768 KB -> L2-resident.
__global__ __launch_bounds__(256, 5) void sim_mfma(
    const unsigned short* __restrict__ bfS, const unsigned short* __restrict__ bfT,
    const float* __restrict__ nrm, float* __restrict__ out)
{
    __shared__ unsigned short As[64 * 128];    // src tile (16 KiB)
    __shared__ unsigned short Bs[64 * 128];    // tgt tile (16 KiB)

    const int tid  = threadIdx.x;
    // XCD swizzle: nwg=4096 divisible by 8 -> simple bijective remap.
    const int flat = blockIdx.x;
    const int swb  = (flat & 7) * 512 + (flat >> 3);
    const int b    = swb >> 10;          // 0..3
    const int i0   = ((swb >> 5) & 31) << 6;   // src-row base (64 rows)
    const int j0   = (swb & 31) << 6;          // tgt-row base (64 rows)

    const char* gA = (const char*)(bfS + ((size_t)b * NDIM + i0) * CDIM);
    const char* gB = (const char*)(bfT + ((size_t)b * MDIM + j0) * CDIM);
    char* lA = (char*)As;
    char* lB = (char*)Bs;
    const int t16 = tid << 4;

    // A,B: 16 KiB each = 4 x (256 threads x 16B).
    #pragma unroll
    for (int it = 0; it < 4; ++it)
        gload_lds16(gA + t16 + it * 4096, lA + t16 + it * 4096);
    #pragma unroll
    for (int it = 0; it < 4; ++it)
        gload_lds16(gB + t16 + it * 4096, lB + t16 + it * 4096);
    __syncthreads();

    const int wave = tid >> 6;
    const int lane = tid & 63;
    const int wm   = (wave & 1) << 5;   // 32-row quadrant
    const int wn   = (wave >> 1) << 5;  // 32-col quadrant
    const int l16  = lane & 15;
    const int q    = lane >> 4;

    f32x4 acc[2][2];
    #pragma unroll
    for (int i = 0; i < 2; ++i)
        #pragma unroll
        for (int j = 0; j < 2; ++j) acc[i][j] = (f32x4){0.f, 0.f, 0.f, 0.f};

    // K = 128 in 4 MFMA steps of 32. Fragment row%16 == l16 -> swz = c ^ l16.
    #pragma unroll
    for (int k0 = 0; k0 < 4; ++k0) {
        int chunk = (k0 << 2) + q;           // (k0*32 + q*8) / 8
        int swz   = (chunk ^ l16) << 3;
        bf16x8 a[2], bv[2];
        #pragma unroll
        for (int i = 0; i < 2; ++i)
            a[i] = *(const bf16x8*)&As[(wm + (i << 4) + l16) * 128 + swz];
        #pragma unroll
        for (int j = 0; j < 2; ++j)
            bv[j] = *(const bf16x8*)&Bs[(wn + (j << 4) + l16) * 128 + swz];
        #pragma unroll
        for (int i = 0; i < 2; ++i)
            #pragma unroll
            for (int j = 0; j < 2; ++j)
                acc[i][j] = __builtin_amdgcn_mfma_f32_16x16x32_bf16(
                    a[i], bv[j], acc[i][j], 0, 0, 0);
    }

    // Norms (L2-hot).
    const float* nrmS = nrm + (size_t)b * NDIM + i0;
    const float* nrmT = nrm + (size_t)NROWS + (size_t)b * MDIM + j0;

    float sq[2][4], isq[2][4];
    #pragma unroll
    for (int i = 0; i < 2; ++i) {
        float4 s4v = *(const float4*)&nrmS[wm + (i << 4) + (q << 2)];
        sq[i][0] = s4v.x; sq[i][1] = s4v.y; sq[i][2] = s4v.z; sq[i][3] = s4v.w;
        #pragma unroll
        for (int r = 0; r < 4; ++r)
            isq[i][r] = __builtin_amdgcn_rsqf(fmaxf(sq[i][r], 1e-24f));
    }
    float tq[2], itq[2];
    #pragma unroll
    for (int j = 0; j < 2; ++j) {
        tq[j]  = nrmT[wn + (j << 4) + l16];
        itq[j] = __builtin_amdgcn_rsqf(fmaxf(tq[j], 1e-24f));
    }

    // Epilogue + nontemporal stores. D layout: col = lane&15, row = q*4+reg.
    f32x2* out2 = (f32x2*)out;
    #pragma unroll
    for (int i = 0; i < 2; ++i) {
        #pragma unroll
        for (int r = 0; r < 4; ++r) {
            int mrow = wm + (i << 4) + (q << 2) + r;
            size_t rowbase = ((size_t)b * NDIM + (size_t)(i0 + mrow)) * MDIM + j0;
            float sqr = sq[i][r], isr = isq[i][r];
            #pragma unroll
            for (int j = 0; j < 2; ++j) {
                int ncol = wn + (j << 4) + l16;
                float d   = acc[i][j][r];
                float cs  = d * isr * itq[j];
                float dsq = fmaf(-2.0f, d, sqr + tq[j]);
                float fd  = __builtin_amdgcn_sqrtf(fmaxf(dsq, 0.0f));
                float fdn = __builtin_amdgcn_rcpf(1.0f + fd);
                f32x2 o; o.x = cs; o.y = fdn;
                __builtin_nontemporal_store(o, &out2[rowbase + ncol]);
            }
        }
    }
}

extern "C" void kernel_launch(void* const* d_in, const int* in_sizes, int n_in,
                              void* d_out, int out_size, void* d_ws, size_t ws_size,
                              hipStream_t stream) {
    const float* src = (const float*)d_in[0];
    const float* tgt = (const float*)d_in[1];
    float* out = (float*)d_out;

    unsigned short* bfS = (unsigned short*)d_ws;                 // 2 MiB
    unsigned short* bfT = bfS + (size_t)NROWS * CDIM;            // 2 MiB
    float*          nrm = (float*)(bfT + (size_t)NROWS * CDIM);  // 64 KiB

    // 16384 rows x 32 lanes = 524288 threads -> 2048 blocks.
    prep_kernel<<<dim3(2048), dim3(256), 0, stream>>>(src, tgt, bfS, nrm);

    // 4096 blocks of 64x64 tiles, XCD-chunk-swizzled in-kernel.
    sim_mfma<<<dim3(4096), dim3(256), 0, stream>>>(bfS, bfT, nrm, out);
}